// Round 1
// baseline (226.793 us; speedup 1.0000x reference)
//
#include <hip/hip_runtime.h>
#include <cmath>

#define IMG_H 512
#define IMG_W 512
#define TH 32            // tile rows (output)
#define TW 64            // tile cols (output)
#define LDSW 84          // LDS row stride in floats (80 used, +4 pad for banks)
#define NPLANES 96       // 32 batch * 3 channels
#define NPIX 25165824.0  // 96*512*512

struct GaussW { float w[11]; };

__constant__ float c_dummy; // (unused; keep file self-contained)

__global__ __launch_bounds__(256, 3) void ssim_main(
    const float* __restrict__ img1, const float* __restrict__ img2,
    float* __restrict__ partials, GaussW gw, int use_atomic, float* __restrict__ out)
{
    __shared__ float V[5][TH][LDSW];
    __shared__ float wsum[4];

    const int tid = threadIdx.x;
    const int plane = blockIdx.z;
    const long base = (long)plane * (IMG_H * IMG_W);
    const int tr0 = blockIdx.y * TH;
    const int tc0 = blockIdx.x * TW;

    // ---------------- Phase 1: vertical conv (global -> LDS) ----------------
    // Compute V[a][r][j] for r in [0,32), j in [0,80): column gc = tc0 + j - 8.
    // Each of 240 active threads owns one column j and 11 consecutive rows,
    // using an 11-deep register ring (sliding window down the column).
    {
        const int j = tid % 80;       // lds col
        const int chunk = tid / 80;   // 0..2 active; tid>=240 idle
        if (chunk < 3) {
            const int gc = tc0 + j - 8;
            const bool cok = (gc >= 0) & (gc < IMG_W);
            const int r0 = chunk * 11;   // first tile-local output row
            float A[11], B[11], Pr[11], Qr[11], Sr[11];
            #pragma unroll
            for (int t = 0; t < 11; ++t) {
                const int gr = tr0 + r0 - 5 + t;
                const bool ok = cok & (gr >= 0) & (gr < IMG_H);
                const long idx = base + (long)gr * IMG_W + gc;
                const float a = ok ? img1[idx] : 0.f;
                const float b = ok ? img2[idx] : 0.f;
                A[t] = a; B[t] = b; Pr[t] = a * a; Qr[t] = b * b; Sr[t] = a * b;
            }
            #pragma unroll
            for (int i = 0; i < 11; ++i) {
                float s0 = 0.f, s1 = 0.f, s2 = 0.f, s3 = 0.f, s4 = 0.f;
                #pragma unroll
                for (int t = 0; t < 11; ++t) {
                    const int sl = (i + t) % 11;   // compile-time after unroll
                    const float wt = gw.w[t];
                    s0 = fmaf(wt, A[sl], s0);
                    s1 = fmaf(wt, B[sl], s1);
                    s2 = fmaf(wt, Pr[sl], s2);
                    s3 = fmaf(wt, Qr[sl], s3);
                    s4 = fmaf(wt, Sr[sl], s4);
                }
                const int r = r0 + i;
                if (r < TH) {
                    V[0][r][j] = s0; V[1][r][j] = s1; V[2][r][j] = s2;
                    V[3][r][j] = s3; V[4][r][j] = s4;
                }
                if (i < 10) {
                    const int gr = tr0 + r0 + i + 6;
                    const bool ok = cok & (gr >= 0) & (gr < IMG_H);
                    const long idx = base + (long)gr * IMG_W + gc;
                    const float a = ok ? img1[idx] : 0.f;
                    const float b = ok ? img2[idx] : 0.f;
                    A[i] = a; B[i] = b; Pr[i] = a * a; Qr[i] = b * b; Sr[i] = a * b;
                }
            }
        }
    }
    __syncthreads();

    // ---------------- Phase 2: horizontal conv + SSIM + reduce ----------------
    // thread -> (row r = tid/8, col-group cg = tid%8 of 8 pixels)
    float lsum = 0.f;
    {
        const int r = tid >> 3;       // 0..31
        const int cg = tid & 7;       // 0..7
        const int c0 = cg * 8;        // first output col (tile-local)
        // load 24 consecutive lds cols [c0 .. c0+23] per array (window needs c0+3..c0+20)
        float f[5][24];
        #pragma unroll
        for (int a = 0; a < 5; ++a) {
            #pragma unroll
            for (int q = 0; q < 6; ++q) {
                const float4 v = *(const float4*)&V[a][r][c0 + q * 4];
                f[a][q * 4 + 0] = v.x; f[a][q * 4 + 1] = v.y;
                f[a][q * 4 + 2] = v.z; f[a][q * 4 + 3] = v.w;
            }
        }
        const float C1f = 0.0001f;   // 0.01^2
        const float C2f = 0.0009f;   // 0.03^2
        #pragma unroll
        for (int c = 0; c < 8; ++c) {
            float m1 = 0.f, m2 = 0.f, e11 = 0.f, e22 = 0.f, e12 = 0.f;
            #pragma unroll
            for (int t = 0; t < 11; ++t) {
                const float wt = gw.w[t];
                m1  = fmaf(wt, f[0][c + 3 + t], m1);
                m2  = fmaf(wt, f[1][c + 3 + t], m2);
                e11 = fmaf(wt, f[2][c + 3 + t], e11);
                e22 = fmaf(wt, f[3][c + 3 + t], e22);
                e12 = fmaf(wt, f[4][c + 3 + t], e12);
            }
            const float mu11 = m1 * m1, mu22 = m2 * m2, mu12 = m1 * m2;
            const float s11 = e11 - mu11, s22 = e22 - mu22, s12 = e12 - mu12;
            const float num = (2.f * mu12 + C1f) * (2.f * s12 + C2f);
            const float den = (mu11 + mu22 + C1f) * (s11 + s22 + C2f);
            lsum += num / den;
        }
    }
    // block reduction
    #pragma unroll
    for (int off = 32; off; off >>= 1) lsum += __shfl_down(lsum, off, 64);
    if ((tid & 63) == 0) wsum[tid >> 6] = lsum;
    __syncthreads();
    if (tid == 0) {
        const float bs = wsum[0] + wsum[1] + wsum[2] + wsum[3];
        if (use_atomic) {
            atomicAdd(out, bs * (float)(1.0 / NPIX));
        } else {
            const int bId = (blockIdx.z * gridDim.y + blockIdx.y) * gridDim.x + blockIdx.x;
            partials[bId] = bs;
        }
    }
}

__global__ __launch_bounds__(256) void ssim_reduce(
    const float* __restrict__ partials, int n, float* __restrict__ out)
{
    const int tid = threadIdx.x;
    double s = 0.0;
    for (int i = tid; i < n; i += 256) s += (double)partials[i];
    #pragma unroll
    for (int off = 32; off; off >>= 1) s += __shfl_down(s, off, 64);
    __shared__ double ws[4];
    if ((tid & 63) == 0) ws[tid >> 6] = s;
    __syncthreads();
    if (tid == 0) out[0] = (float)(((ws[0] + ws[1]) + (ws[2] + ws[3])) / NPIX);
}

extern "C" void kernel_launch(void* const* d_in, const int* in_sizes, int n_in,
                              void* d_out, int out_size, void* d_ws, size_t ws_size,
                              hipStream_t stream) {
    const float* img1 = (const float*)d_in[0];
    const float* img2 = (const float*)d_in[1];
    float* out = (float*)d_out;

    // Gaussian window (host, double precision, normalized)
    GaussW gw;
    {
        double g[11], sum = 0.0;
        for (int i = 0; i < 11; ++i) {
            const double c = (double)(i - 5);
            g[i] = std::exp(-(c * c) / 4.5);   // 2*sigma^2 = 4.5
            sum += g[i];
        }
        for (int i = 0; i < 11; ++i) gw.w[i] = (float)(g[i] / sum);
    }

    dim3 grid(IMG_W / TW, IMG_H / TH, NPLANES);   // 8 x 16 x 96
    const int nPart = grid.x * grid.y * grid.z;   // 12288

    if (ws_size >= (size_t)nPart * sizeof(float)) {
        // deterministic two-stage reduction
        ssim_main<<<grid, 256, 0, stream>>>(img1, img2, (float*)d_ws, gw, 0, out);
        ssim_reduce<<<1, 256, 0, stream>>>((float*)d_ws, nPart, out);
    } else {
        // fallback: atomic accumulation (still within tolerance)
        hipMemsetAsync(d_out, 0, sizeof(float), stream);
        ssim_main<<<grid, 256, 0, stream>>>(img1, img2, nullptr, gw, 1, out);
    }
}

// Round 2
// 178.823 us; speedup vs baseline: 1.2683x; 1.2683x over previous
//
#include <hip/hip_runtime.h>
#include <cmath>

#define IMG_H 512
#define IMG_W 512
#define TH 32            // tile rows (output)
#define TW 64            // tile cols (output)
#define LDSW 84          // LDS row stride in floats (80 used, +4 pad; 84%32=20 spreads banks, mult-of-4 keeps b128 alignment)
#define NPLANES 96       // 32 batch * 3 channels
#define NPIX 25165824.0  // 96*512*512

struct GaussW { float w[11]; };

__global__ __launch_bounds__(256, 3) void ssim_main(
    const float* __restrict__ img1, const float* __restrict__ img2,
    float* __restrict__ partials, GaussW gw, int use_atomic, float* __restrict__ out)
{
    __shared__ float V[5][TH][LDSW];
    __shared__ float wsum[4];

    const int tid = threadIdx.x;
    const int plane = blockIdx.z;
    const long base = (long)plane * (IMG_H * IMG_W);
    const int tr0 = blockIdx.y * TH;
    const int tc0 = blockIdx.x * TW;

    // ---------------- Phase 1: vertical conv (global -> LDS) ----------------
    // V[a][r][j], r in [0,32), j in [0,80): column gc = tc0 + j - 8.
    // 240 active threads: one column j each, 11 consecutive output rows,
    // 11-deep register ring sliding down the column.
    {
        const int j = tid % 80;       // lds col
        const int chunk = tid / 80;   // 0..2 active; tid>=240 idle
        if (chunk < 3) {
            const int gc = tc0 + j - 8;
            const bool cok = (gc >= 0) & (gc < IMG_W);
            const int r0 = chunk * 11;   // first tile-local output row
            float A[11], B[11], Pr[11], Qr[11], Sr[11];
            #pragma unroll
            for (int t = 0; t < 11; ++t) {
                const int gr = tr0 + r0 - 5 + t;
                const bool ok = cok & (gr >= 0) & (gr < IMG_H);
                const long idx = base + (long)gr * IMG_W + gc;
                const float a = ok ? img1[idx] : 0.f;
                const float b = ok ? img2[idx] : 0.f;
                A[t] = a; B[t] = b; Pr[t] = a * a; Qr[t] = b * b; Sr[t] = a * b;
            }
            #pragma unroll
            for (int i = 0; i < 11; ++i) {
                const int r = r0 + i;
                if (r < TH) {
                    float s0 = 0.f, s1 = 0.f, s2 = 0.f, s3 = 0.f, s4 = 0.f;
                    #pragma unroll
                    for (int t = 0; t < 11; ++t) {
                        const int sl = (i + t) % 11;   // compile-time after unroll
                        const float wt = gw.w[t];
                        s0 = fmaf(wt, A[sl], s0);
                        s1 = fmaf(wt, B[sl], s1);
                        s2 = fmaf(wt, Pr[sl], s2);
                        s3 = fmaf(wt, Qr[sl], s3);
                        s4 = fmaf(wt, Sr[sl], s4);
                    }
                    V[0][r][j] = s0; V[1][r][j] = s1; V[2][r][j] = s2;
                    V[3][r][j] = s3; V[4][r][j] = s4;
                }
                // load next input row only if it feeds a kept output row
                if (i < 10 && (r0 + i + 1) < TH) {
                    const int gr = tr0 + r0 + i + 6;
                    const bool ok = cok & (gr >= 0) & (gr < IMG_H);
                    const long idx = base + (long)gr * IMG_W + gc;
                    const float a = ok ? img1[idx] : 0.f;
                    const float b = ok ? img2[idx] : 0.f;
                    A[i] = a; B[i] = b; Pr[i] = a * a; Qr[i] = b * b; Sr[i] = a * b;
                }
            }
        }
    }
    __syncthreads();

    // ---------------- Phase 2: horizontal conv + SSIM + reduce ----------------
    // One array at a time: 6 x b128 LDS loads (24 floats live) -> 8 conv sums.
    // Peak live ~ 24 staging + 40 acc -> compiler can register-stage everything.
    float lsum = 0.f;
    {
        const int r = tid >> 3;       // 0..31
        const int c0 = (tid & 7) * 8; // first output col (tile-local)
        float acc[5][8];              // fully static-indexed after unroll
        #pragma unroll
        for (int a = 0; a < 5; ++a) {
            float fb[24];
            #pragma unroll
            for (int q = 0; q < 6; ++q) {
                const float4 v = *(const float4*)&V[a][r][c0 + 4 * q];
                fb[4 * q + 0] = v.x; fb[4 * q + 1] = v.y;
                fb[4 * q + 2] = v.z; fb[4 * q + 3] = v.w;
            }
            #pragma unroll
            for (int c = 0; c < 8; ++c) {
                float s = 0.f;
                #pragma unroll
                for (int t = 0; t < 11; ++t)
                    s = fmaf(gw.w[t], fb[c + 3 + t], s);
                acc[a][c] = s;
            }
        }
        const float C1f = 0.0001f;   // 0.01^2
        const float C2f = 0.0009f;   // 0.03^2
        #pragma unroll
        for (int c = 0; c < 8; ++c) {
            const float m1 = acc[0][c], m2 = acc[1][c];
            const float e11 = acc[2][c], e22 = acc[3][c], e12 = acc[4][c];
            const float mu11 = m1 * m1, mu22 = m2 * m2, mu12 = m1 * m2;
            const float s11 = e11 - mu11, s22 = e22 - mu22, s12 = e12 - mu12;
            const float num = (2.f * mu12 + C1f) * (2.f * s12 + C2f);
            const float den = (mu11 + mu22 + C1f) * (s11 + s22 + C2f);
            // fast reciprocal + 1 Newton step (error ~2^-28; tolerance is 2.7e-4)
            float rcp = __builtin_amdgcn_rcpf(den);
            rcp = rcp * (2.f - den * rcp);
            lsum = fmaf(num, rcp, lsum);
        }
    }
    // block reduction
    #pragma unroll
    for (int off = 32; off; off >>= 1) lsum += __shfl_down(lsum, off, 64);
    if ((tid & 63) == 0) wsum[tid >> 6] = lsum;
    __syncthreads();
    if (tid == 0) {
        const float bs = wsum[0] + wsum[1] + wsum[2] + wsum[3];
        if (use_atomic) {
            atomicAdd(out, bs * (float)(1.0 / NPIX));
        } else {
            const int bId = (blockIdx.z * gridDim.y + blockIdx.y) * gridDim.x + blockIdx.x;
            partials[bId] = bs;
        }
    }
}

__global__ __launch_bounds__(256) void ssim_reduce(
    const float* __restrict__ partials, int n, float* __restrict__ out)
{
    const int tid = threadIdx.x;
    double s = 0.0;
    for (int i = tid; i < n; i += 256) s += (double)partials[i];
    #pragma unroll
    for (int off = 32; off; off >>= 1) s += __shfl_down(s, off, 64);
    __shared__ double ws[4];
    if ((tid & 63) == 0) ws[tid >> 6] = s;
    __syncthreads();
    if (tid == 0) out[0] = (float)(((ws[0] + ws[1]) + (ws[2] + ws[3])) / NPIX);
}

extern "C" void kernel_launch(void* const* d_in, const int* in_sizes, int n_in,
                              void* d_out, int out_size, void* d_ws, size_t ws_size,
                              hipStream_t stream) {
    const float* img1 = (const float*)d_in[0];
    const float* img2 = (const float*)d_in[1];
    float* out = (float*)d_out;

    // Gaussian window (host, double precision, normalized)
    GaussW gw;
    {
        double g[11], sum = 0.0;
        for (int i = 0; i < 11; ++i) {
            const double c = (double)(i - 5);
            g[i] = std::exp(-(c * c) / 4.5);   // 2*sigma^2 = 4.5
            sum += g[i];
        }
        for (int i = 0; i < 11; ++i) gw.w[i] = (float)(g[i] / sum);
    }

    dim3 grid(IMG_W / TW, IMG_H / TH, NPLANES);   // 8 x 16 x 96
    const int nPart = grid.x * grid.y * grid.z;   // 12288

    if (ws_size >= (size_t)nPart * sizeof(float)) {
        // deterministic two-stage reduction
        ssim_main<<<grid, 256, 0, stream>>>(img1, img2, (float*)d_ws, gw, 0, out);
        ssim_reduce<<<1, 256, 0, stream>>>((float*)d_ws, nPart, out);
    } else {
        // fallback: atomic accumulation (still within tolerance)
        hipMemsetAsync(d_out, 0, sizeof(float), stream);
        ssim_main<<<grid, 256, 0, stream>>>(img1, img2, nullptr, gw, 1, out);
    }
}

// Round 3
// 135.397 us; speedup vs baseline: 1.6750x; 1.3207x over previous
//
#include <hip/hip_runtime.h>
#include <cmath>

#define IMG_H 512
#define IMG_W 512
#define TH 32            // tile rows (output)
#define TW 64            // tile cols (output)
#define LDSW 83          // ODD stride: bank = (19r + 8cg) % 32 -> all 32 banks x2 lanes, conflict-free
#define NPLANES 96       // 32 batch * 3 channels
#define NPIX 25165824.0  // 96*512*512

struct GaussW { float w[11]; };

__global__ __launch_bounds__(256, 3) void ssim_main(
    const float* __restrict__ img1, const float* __restrict__ img2,
    float* __restrict__ partials, GaussW gw, int use_atomic, float* __restrict__ out)
{
    __shared__ float V[5][TH][LDSW];   // 5*32*83*4 = 53120 B
    __shared__ float wsum[4];

    const int tid = threadIdx.x;
    const int plane = blockIdx.z;
    const long base = (long)plane * (IMG_H * IMG_W);
    const int tr0 = blockIdx.y * TH;
    const int tc0 = blockIdx.x * TW;

    // ---------------- Phase 1: vertical conv, accumulator-resident scatter ----
    // 240 active threads: one lds column j each, 11 output rows (chunk r0 = {0,11,22}).
    // Stream 21 input rows once; scatter each row's 5 products into 55 static
    // accumulators. Accumulators can't be rematerialized -> forces registers,
    // loads stay at 42/thread.
    {
        const int j = tid % 80;       // lds col
        const int chunk = tid / 80;   // 0..2 active; tid>=240 idle
        if (chunk < 3) {
            const int gc = tc0 + j - 8;
            const float cmask = (gc >= 0 && gc < IMG_W) ? 1.f : 0.f;
            const int gcc = min(max(gc, 0), IMG_W - 1);   // v_med3
            const int r0 = chunk * 11;

            float aA[11], aB[11], aP[11], aQ[11], aS[11];
            #pragma unroll
            for (int o = 0; o < 11; ++o) { aA[o]=0.f; aB[o]=0.f; aP[o]=0.f; aQ[o]=0.f; aS[o]=0.f; }

            #pragma unroll
            for (int ii = 0; ii < 21; ++ii) {
                const int gr = tr0 + r0 - 5 + ii;
                const float rmask = (gr >= 0 && gr < IMG_H) ? cmask : 0.f;
                const int grc = min(max(gr, 0), IMG_H - 1);
                const long idx = base + (long)grc * IMG_W + gcc;
                const float a = img1[idx] * rmask;
                const float b = img2[idx] * rmask;
                const float p = a * a, q = b * b, s = a * b;
                #pragma unroll
                for (int o = 0; o < 11; ++o) {
                    if (o >= ii - 10 && o <= ii) {          // compile-time predicate
                        const float wt = gw.w[ii - o];      // tap = gr-(R-5) = ii-o
                        aA[o] = fmaf(wt, a, aA[o]);
                        aB[o] = fmaf(wt, b, aB[o]);
                        aP[o] = fmaf(wt, p, aP[o]);
                        aQ[o] = fmaf(wt, q, aQ[o]);
                        aS[o] = fmaf(wt, s, aS[o]);
                    }
                }
            }
            #pragma unroll
            for (int o = 0; o < 11; ++o) {
                const int r = r0 + o;
                if (r0 + o < TH) {   // only chunk2/o=10 is ever false
                    V[0][r][j] = aA[o]; V[1][r][j] = aB[o]; V[2][r][j] = aP[o];
                    V[3][r][j] = aQ[o]; V[4][r][j] = aS[o];
                }
            }
        }
    }
    __syncthreads();

    // ---------------- Phase 2: horizontal conv, per-column scatter ------------
    // Thread -> (row r, 8 output cols at c0). Read each of 18 window columns
    // ONCE (b32, conflict-free with odd stride), scatter into 8 accumulators.
    float lsum = 0.f;
    {
        const int r = tid >> 3;        // 0..31
        const int c0 = (tid & 7) * 8;  // local output col group
        float m1[8], m2[8], e11[8], e22[8], e12[8];
        #pragma unroll
        for (int c = 0; c < 8; ++c) { m1[c]=0.f; m2[c]=0.f; e11[c]=0.f; e22[c]=0.f; e12[c]=0.f; }

        #pragma unroll
        for (int k = 3; k <= 20; ++k) {          // window cols c0+3 .. c0+20
            const float vA = V[0][r][c0 + k];
            const float vB = V[1][r][c0 + k];
            const float vP = V[2][r][c0 + k];
            const float vQ = V[3][r][c0 + k];
            const float vS = V[4][r][c0 + k];
            #pragma unroll
            for (int c = 0; c < 8; ++c) {
                if (k - 13 <= c && c <= k - 3) {            // compile-time
                    const float wt = gw.w[k - 3 - c];
                    m1[c]  = fmaf(wt, vA, m1[c]);
                    m2[c]  = fmaf(wt, vB, m2[c]);
                    e11[c] = fmaf(wt, vP, e11[c]);
                    e22[c] = fmaf(wt, vQ, e22[c]);
                    e12[c] = fmaf(wt, vS, e12[c]);
                }
            }
        }
        const float C1f = 0.0001f;   // 0.01^2
        const float C2f = 0.0009f;   // 0.03^2
        #pragma unroll
        for (int c = 0; c < 8; ++c) {
            const float mu11 = m1[c] * m1[c], mu22 = m2[c] * m2[c], mu12 = m1[c] * m2[c];
            const float s11 = e11[c] - mu11, s22 = e22[c] - mu22, s12 = e12[c] - mu12;
            const float num = (2.f * mu12 + C1f) * (2.f * s12 + C2f);
            const float den = (mu11 + mu22 + C1f) * (s11 + s22 + C2f);
            float rcp = __builtin_amdgcn_rcpf(den);
            rcp = rcp * (2.f - den * rcp);      // 1 Newton step
            lsum = fmaf(num, rcp, lsum);
        }
    }
    // block reduction
    #pragma unroll
    for (int off = 32; off; off >>= 1) lsum += __shfl_down(lsum, off, 64);
    if ((tid & 63) == 0) wsum[tid >> 6] = lsum;
    __syncthreads();
    if (tid == 0) {
        const float bs = wsum[0] + wsum[1] + wsum[2] + wsum[3];
        if (use_atomic) {
            atomicAdd(out, bs * (float)(1.0 / NPIX));
        } else {
            const int bId = (blockIdx.z * gridDim.y + blockIdx.y) * gridDim.x + blockIdx.x;
            partials[bId] = bs;
        }
    }
}

__global__ __launch_bounds__(256) void ssim_reduce(
    const float* __restrict__ partials, int n, float* __restrict__ out)
{
    const int tid = threadIdx.x;
    double s = 0.0;
    for (int i = tid; i < n; i += 256) s += (double)partials[i];
    #pragma unroll
    for (int off = 32; off; off >>= 1) s += __shfl_down(s, off, 64);
    __shared__ double ws[4];
    if ((tid & 63) == 0) ws[tid >> 6] = s;
    __syncthreads();
    if (tid == 0) out[0] = (float)(((ws[0] + ws[1]) + (ws[2] + ws[3])) / NPIX);
}

extern "C" void kernel_launch(void* const* d_in, const int* in_sizes, int n_in,
                              void* d_out, int out_size, void* d_ws, size_t ws_size,
                              hipStream_t stream) {
    const float* img1 = (const float*)d_in[0];
    const float* img2 = (const float*)d_in[1];
    float* out = (float*)d_out;

    // Gaussian window (host, double precision, normalized)
    GaussW gw;
    {
        double g[11], sum = 0.0;
        for (int i = 0; i < 11; ++i) {
            const double c = (double)(i - 5);
            g[i] = std::exp(-(c * c) / 4.5);   // 2*sigma^2 = 4.5
            sum += g[i];
        }
        for (int i = 0; i < 11; ++i) gw.w[i] = (float)(g[i] / sum);
    }

    dim3 grid(IMG_W / TW, IMG_H / TH, NPLANES);   // 8 x 16 x 96
    const int nPart = grid.x * grid.y * grid.z;   // 12288

    if (ws_size >= (size_t)nPart * sizeof(float)) {
        // deterministic two-stage reduction
        ssim_main<<<grid, 256, 0, stream>>>(img1, img2, (float*)d_ws, gw, 0, out);
        ssim_reduce<<<1, 256, 0, stream>>>((float*)d_ws, nPart, out);
    } else {
        // fallback: atomic accumulation (still within tolerance)
        hipMemsetAsync(d_out, 0, sizeof(float), stream);
        ssim_main<<<grid, 256, 0, stream>>>(img1, img2, nullptr, gw, 1, out);
    }
}

// Round 4
// 134.700 us; speedup vs baseline: 1.6837x; 1.0052x over previous
//
#include <hip/hip_runtime.h>
#include <cmath>

#define IMG_H 512
#define IMG_W 512
#define TH 32            // tile rows (output)
#define TW 64            // tile cols (output)
#define LDSW 83          // ODD stride: phase-2 b32 reads hit all 32 banks x2 lanes (conflict-free)
#define NPLANES 96       // 32 batch * 3 channels
#define NPIX 25165824.0  // 96*512*512

struct GaussW { float w[11]; };

__global__ __launch_bounds__(256, 3) void ssim_main(
    const float* __restrict__ img1, const float* __restrict__ img2,
    float* __restrict__ partials, GaussW gw, int use_atomic, float* __restrict__ out)
{
    __shared__ float V[5][TH][LDSW];   // 53120 B -> 3 blocks/CU
    __shared__ float wsum[4];

    const int tid = threadIdx.x;
    const int plane = blockIdx.z;
    const int tr0 = blockIdx.y * TH;
    const int tc0 = blockIdx.x * TW;
    const float* __restrict__ plane1 = img1 + ((size_t)plane << 18);  // uniform -> SGPR base
    const float* __restrict__ plane2 = img2 + ((size_t)plane << 18);

    // ---------------- Phase 1: vertical conv, accumulator-resident scatter ----
    // 240 threads: one lds column j each, 11 output rows (chunk r0 = {0,11,22}).
    // Stream 21 input rows once; scatter each row's 5 products into 55 static
    // accumulators (first-touch init, no zero-fill).
    {
        const int j = tid % 80;       // lds col
        const int chunk = tid / 80;   // 0..2 active; tid>=240 idle
        if (chunk < 3) {
            const int r0 = chunk * 11;
            const int gc = tc0 + j - 8;
            float aA[11], aB[11], aP[11], aQ[11], aS[11];

            const bool interior = (blockIdx.x >= 1) & (blockIdx.x <= 6)
                                & (blockIdx.y >= 1) & (blockIdx.y <= 14);
            if (interior) {
                // fast path: no clamps/masks; SGPR base + 32-bit voffset,
                // row steps are compile-time constants
                const uint32_t off0 = (uint32_t)((tr0 + r0 - 5) * IMG_W + gc);
                #pragma unroll
                for (int ii = 0; ii < 21; ++ii) {
                    const float a = plane1[off0 + (uint32_t)(ii * IMG_W)];
                    const float b = plane2[off0 + (uint32_t)(ii * IMG_W)];
                    const float p = a * a, q = b * b, s = a * b;
                    #pragma unroll
                    for (int o = 0; o < 11; ++o) {
                        if (o <= ii && ii <= o + 10) {          // compile-time
                            const float wt = gw.w[ii - o];
                            if (ii == o) {                       // first touch
                                aA[o] = wt * a; aB[o] = wt * b; aP[o] = wt * p;
                                aQ[o] = wt * q; aS[o] = wt * s;
                            } else {
                                aA[o] = fmaf(wt, a, aA[o]);
                                aB[o] = fmaf(wt, b, aB[o]);
                                aP[o] = fmaf(wt, p, aP[o]);
                                aQ[o] = fmaf(wt, q, aQ[o]);
                                aS[o] = fmaf(wt, s, aS[o]);
                            }
                        }
                    }
                }
            } else {
                // edge path: clamp + zero-mask (zero padding semantics)
                const float cmask = (gc >= 0 && gc < IMG_W) ? 1.f : 0.f;
                const int gcc = min(max(gc, 0), IMG_W - 1);
                #pragma unroll
                for (int ii = 0; ii < 21; ++ii) {
                    const int gr = tr0 + r0 - 5 + ii;
                    const float rmask = (gr >= 0 && gr < IMG_H) ? cmask : 0.f;
                    const int grc = min(max(gr, 0), IMG_H - 1);
                    const uint32_t idx = (uint32_t)(grc * IMG_W + gcc);
                    const float a = plane1[idx] * rmask;
                    const float b = plane2[idx] * rmask;
                    const float p = a * a, q = b * b, s = a * b;
                    #pragma unroll
                    for (int o = 0; o < 11; ++o) {
                        if (o <= ii && ii <= o + 10) {
                            const float wt = gw.w[ii - o];
                            if (ii == o) {
                                aA[o] = wt * a; aB[o] = wt * b; aP[o] = wt * p;
                                aQ[o] = wt * q; aS[o] = wt * s;
                            } else {
                                aA[o] = fmaf(wt, a, aA[o]);
                                aB[o] = fmaf(wt, b, aB[o]);
                                aP[o] = fmaf(wt, p, aP[o]);
                                aQ[o] = fmaf(wt, q, aQ[o]);
                                aS[o] = fmaf(wt, s, aS[o]);
                            }
                        }
                    }
                }
            }
            #pragma unroll
            for (int o = 0; o < 11; ++o) {
                const int r = r0 + o;
                if (r0 + o < TH) {   // only chunk2/o=10 is false
                    V[0][r][j] = aA[o]; V[1][r][j] = aB[o]; V[2][r][j] = aP[o];
                    V[3][r][j] = aQ[o]; V[4][r][j] = aS[o];
                }
            }
        }
    }
    __syncthreads();

    // ---------------- Phase 2: horizontal conv, per-column scatter ------------
    // One base vgpr; all 90 reads are ds_read_b32 with immediate offsets.
    float lsum = 0.f;
    {
        const int r = tid >> 3;        // 0..31
        const int c0 = (tid & 7) * 8;  // local output col group
        const float* Vb = &V[0][r][c0];
        float m1[8], m2[8], e11[8], e22[8], e12[8];

        #pragma unroll
        for (int k = 3; k <= 20; ++k) {          // window cols c0+3 .. c0+20
            const float vA = Vb[k];
            const float vB = Vb[1 * TH * LDSW + k];
            const float vP = Vb[2 * TH * LDSW + k];
            const float vQ = Vb[3 * TH * LDSW + k];
            const float vS = Vb[4 * TH * LDSW + k];
            #pragma unroll
            for (int c = 0; c < 8; ++c) {
                if (k - 13 <= c && c <= k - 3) {            // compile-time
                    const float wt = gw.w[k - 3 - c];
                    if (k == c + 3) {                        // first touch
                        m1[c] = wt * vA; m2[c] = wt * vB; e11[c] = wt * vP;
                        e22[c] = wt * vQ; e12[c] = wt * vS;
                    } else {
                        m1[c]  = fmaf(wt, vA, m1[c]);
                        m2[c]  = fmaf(wt, vB, m2[c]);
                        e11[c] = fmaf(wt, vP, e11[c]);
                        e22[c] = fmaf(wt, vQ, e22[c]);
                        e12[c] = fmaf(wt, vS, e12[c]);
                    }
                }
            }
        }
        #pragma unroll
        for (int c = 0; c < 8; ++c) {
            const float a1 = m1[c], a2 = m2[c];
            const float den1 = fmaf(a1, a1, fmaf(a2, a2, 0.0001f)); // mu11+mu22+C1
            const float s11  = fmaf(-a1, a1, e11[c]);
            const float s22  = fmaf(-a2, a2, e22[c]);
            const float s12  = fmaf(-a1, a2, e12[c]);
            const float mu12 = a1 * a2;
            const float num  = fmaf(2.f, mu12, 0.0001f) * fmaf(2.f, s12, 0.0009f);
            const float den  = den1 * (s11 + s22 + 0.0009f);
            lsum = fmaf(num, __builtin_amdgcn_rcpf(den), lsum);     // rcp ~1ulp, tol 2.7e-4
        }
    }
    // block reduction
    #pragma unroll
    for (int off = 32; off; off >>= 1) lsum += __shfl_down(lsum, off, 64);
    if ((tid & 63) == 0) wsum[tid >> 6] = lsum;
    __syncthreads();
    if (tid == 0) {
        const float bs = wsum[0] + wsum[1] + wsum[2] + wsum[3];
        if (use_atomic) {
            atomicAdd(out, bs * (float)(1.0 / NPIX));
        } else {
            const int bId = (blockIdx.z * gridDim.y + blockIdx.y) * gridDim.x + blockIdx.x;
            partials[bId] = bs;
        }
    }
}

__global__ __launch_bounds__(256) void ssim_reduce(
    const float* __restrict__ partials, int n, float* __restrict__ out)
{
    const int tid = threadIdx.x;
    double s = 0.0;
    for (int i = tid; i < n; i += 256) s += (double)partials[i];
    #pragma unroll
    for (int off = 32; off; off >>= 1) s += __shfl_down(s, off, 64);
    __shared__ double ws[4];
    if ((tid & 63) == 0) ws[tid >> 6] = s;
    __syncthreads();
    if (tid == 0) out[0] = (float)(((ws[0] + ws[1]) + (ws[2] + ws[3])) / NPIX);
}

extern "C" void kernel_launch(void* const* d_in, const int* in_sizes, int n_in,
                              void* d_out, int out_size, void* d_ws, size_t ws_size,
                              hipStream_t stream) {
    const float* img1 = (const float*)d_in[0];
    const float* img2 = (const float*)d_in[1];
    float* out = (float*)d_out;

    // Gaussian window (host, double precision, normalized)
    GaussW gw;
    {
        double g[11], sum = 0.0;
        for (int i = 0; i < 11; ++i) {
            const double c = (double)(i - 5);
            g[i] = std::exp(-(c * c) / 4.5);   // 2*sigma^2 = 4.5
            sum += g[i];
        }
        for (int i = 0; i < 11; ++i) gw.w[i] = (float)(g[i] / sum);
    }

    dim3 grid(IMG_W / TW, IMG_H / TH, NPLANES);   // 8 x 16 x 96
    const int nPart = grid.x * grid.y * grid.z;   // 12288

    if (ws_size >= (size_t)nPart * sizeof(float)) {
        // deterministic two-stage reduction
        ssim_main<<<grid, 256, 0, stream>>>(img1, img2, (float*)d_ws, gw, 0, out);
        ssim_reduce<<<1, 256, 0, stream>>>((float*)d_ws, nPart, out);
    } else {
        // fallback: atomic accumulation (still within tolerance)
        hipMemsetAsync(d_out, 0, sizeof(float), stream);
        ssim_main<<<grid, 256, 0, stream>>>(img1, img2, nullptr, gw, 1, out);
    }
}

// Round 5
// 115.169 us; speedup vs baseline: 1.9692x; 1.1696x over previous
//
#include <hip/hip_runtime.h>
#include <cmath>

#define IMG_H 512
#define IMG_W 512
#define TH 32            // tile rows (output)
#define TW 64            // tile cols (output)
#define LDSW 83          // odd stride: b32 reads hit all 32 banks x2; b64 reads uniform over 16 bank-pairs
#define NPLANES 96       // 32 batch * 3 channels
#define NPIX 25165824.0  // 96*512*512

typedef float vf2 __attribute__((ext_vector_type(2)));

struct GaussW { float w[11]; };

__global__ __launch_bounds__(256, 3) void ssim_main(
    const float* __restrict__ img1, const float* __restrict__ img2,
    float* __restrict__ partials, GaussW gw, int use_atomic, float* __restrict__ out)
{
    // Interleaved pair layout: (A,B) and (P,Q) share weights -> v_pk_fma_f32.
    __shared__ vf2   VAB[TH][LDSW];   // 21248 B
    __shared__ vf2   VPQ[TH][LDSW];   // 21248 B
    __shared__ float VS [TH][LDSW];   // 10624 B   (total 53152 -> 3 blocks/CU)
    __shared__ float wsum[4];

    const int tid = threadIdx.x;
    const int plane = blockIdx.z;
    const int tr0 = blockIdx.y * TH;
    const int tc0 = blockIdx.x * TW;
    const float* __restrict__ plane1 = img1 + ((size_t)plane << 18);  // uniform -> SGPR base
    const float* __restrict__ plane2 = img2 + ((size_t)plane << 18);

    // ---------------- Phase 1: vertical conv, packed accumulator scatter ------
    // 240 threads: one lds column j each, 11 output rows (chunk r0 = {0,11,22}).
    // Single path (no interior/edge split -- round-4's dual path caused scratch
    // demotion of the accumulator arrays: WRITE_SIZE 0.4->22.8 MB).
    {
        const int j = tid % 80;       // lds col
        const int chunk = tid / 80;   // 0..2 active; tid>=240 idle
        if (chunk < 3) {
            const int r0 = chunk * 11;
            const int gc = tc0 + j - 8;
            const float cmask = (gc >= 0 && gc < IMG_W) ? 1.f : 0.f;
            const int gcc = min(max(gc, 0), IMG_W - 1);   // v_med3

            vf2 aAB[11], aPQ[11];
            float aS[11];

            #pragma unroll
            for (int ii = 0; ii < 21; ++ii) {
                const int gr = tr0 + r0 - 5 + ii;
                const float rmask = (gr >= 0 && gr < IMG_H) ? cmask : 0.f;
                const int grc = min(max(gr, 0), IMG_H - 1);
                const uint32_t idx = (uint32_t)(grc * IMG_W + gcc);
                const float a = plane1[idx] * rmask;
                const float b = plane2[idx] * rmask;
                const vf2 ab = { a, b };
                const vf2 pq = ab * ab;            // v_pk_mul_f32
                const float s = a * b;
                #pragma unroll
                for (int o = 0; o < 11; ++o) {
                    if (o <= ii && ii <= o + 10) {          // compile-time predicate
                        const float wt = gw.w[ii - o];
                        const vf2 wtv = { wt, wt };
                        if (ii == o) {                       // first touch
                            aAB[o] = wtv * ab;
                            aPQ[o] = wtv * pq;
                            aS[o]  = wt * s;
                        } else {
                            aAB[o] = __builtin_elementwise_fma(wtv, ab, aAB[o]);
                            aPQ[o] = __builtin_elementwise_fma(wtv, pq, aPQ[o]);
                            aS[o]  = fmaf(wt, s, aS[o]);
                        }
                    }
                }
            }
            #pragma unroll
            for (int o = 0; o < 11; ++o) {
                const int r = r0 + o;
                if (r0 + o < TH) {   // only chunk2/o=10 is false
                    VAB[r][j] = aAB[o];        // ds_write_b64
                    VPQ[r][j] = aPQ[o];        // ds_write_b64
                    VS [r][j] = aS[o];         // ds_write_b32
                }
            }
        }
    }
    __syncthreads();

    // ---------------- Phase 2: horizontal conv, packed per-column scatter -----
    // Thread -> (row r, 8 output cols at c0). Read each window col once
    // (2x ds_read_b64 + 1x ds_read_b32), scatter into packed accumulators.
    float lsum = 0.f;
    {
        const int r = tid >> 3;        // 0..31
        const int c0 = (tid & 7) * 8;  // local output col group
        const vf2*   __restrict__ bAB = &VAB[r][c0];
        const vf2*   __restrict__ bPQ = &VPQ[r][c0];
        const float* __restrict__ bS  = &VS [r][c0];

        vf2 mAB[8], ePQ[8];
        float e12[8];

        #pragma unroll
        for (int k = 3; k <= 20; ++k) {          // window cols c0+3 .. c0+20
            const vf2   vab = bAB[k];            // (muA, muB) contribution
            const vf2   vpq = bPQ[k];
            const float vs  = bS[k];
            #pragma unroll
            for (int c = 0; c < 8; ++c) {
                if (k - 13 <= c && c <= k - 3) {            // compile-time
                    const float wt = gw.w[k - 3 - c];
                    const vf2 wtv = { wt, wt };
                    if (k == c + 3) {                        // first touch
                        mAB[c] = wtv * vab;
                        ePQ[c] = wtv * vpq;
                        e12[c] = wt * vs;
                    } else {
                        mAB[c] = __builtin_elementwise_fma(wtv, vab, mAB[c]);
                        ePQ[c] = __builtin_elementwise_fma(wtv, vpq, ePQ[c]);
                        e12[c] = fmaf(wt, vs, e12[c]);
                    }
                }
            }
        }
        #pragma unroll
        for (int c = 0; c < 8; ++c) {
            const float a1 = mAB[c].x, a2 = mAB[c].y;
            const float den1 = fmaf(a1, a1, fmaf(a2, a2, 0.0001f)); // mu11+mu22+C1
            const float s11  = fmaf(-a1, a1, ePQ[c].x);
            const float s22  = fmaf(-a2, a2, ePQ[c].y);
            const float s12  = fmaf(-a1, a2, e12[c]);
            const float mu12 = a1 * a2;
            const float num  = fmaf(2.f, mu12, 0.0001f) * fmaf(2.f, s12, 0.0009f);
            const float den  = den1 * (s11 + s22 + 0.0009f);
            lsum = fmaf(num, __builtin_amdgcn_rcpf(den), lsum);     // rcp ~1ulp, tol 2.7e-4
        }
    }
    // block reduction
    #pragma unroll
    for (int off = 32; off; off >>= 1) lsum += __shfl_down(lsum, off, 64);
    if ((tid & 63) == 0) wsum[tid >> 6] = lsum;
    __syncthreads();
    if (tid == 0) {
        const float bs = wsum[0] + wsum[1] + wsum[2] + wsum[3];
        if (use_atomic) {
            atomicAdd(out, bs * (float)(1.0 / NPIX));
        } else {
            const int bId = (blockIdx.z * gridDim.y + blockIdx.y) * gridDim.x + blockIdx.x;
            partials[bId] = bs;
        }
    }
}

__global__ __launch_bounds__(256) void ssim_reduce(
    const float* __restrict__ partials, int n, float* __restrict__ out)
{
    const int tid = threadIdx.x;
    double s = 0.0;
    for (int i = tid; i < n; i += 256) s += (double)partials[i];
    #pragma unroll
    for (int off = 32; off; off >>= 1) s += __shfl_down(s, off, 64);
    __shared__ double ws[4];
    if ((tid & 63) == 0) ws[tid >> 6] = s;
    __syncthreads();
    if (tid == 0) out[0] = (float)(((ws[0] + ws[1]) + (ws[2] + ws[3])) / NPIX);
}

extern "C" void kernel_launch(void* const* d_in, const int* in_sizes, int n_in,
                              void* d_out, int out_size, void* d_ws, size_t ws_size,
                              hipStream_t stream) {
    const float* img1 = (const float*)d_in[0];
    const float* img2 = (const float*)d_in[1];
    float* out = (float*)d_out;

    // Gaussian window (host, double precision, normalized)
    GaussW gw;
    {
        double g[11], sum = 0.0;
        for (int i = 0; i < 11; ++i) {
            const double c = (double)(i - 5);
            g[i] = std::exp(-(c * c) / 4.5);   // 2*sigma^2 = 4.5
            sum += g[i];
        }
        for (int i = 0; i < 11; ++i) gw.w[i] = (float)(g[i] / sum);
    }

    dim3 grid(IMG_W / TW, IMG_H / TH, NPLANES);   // 8 x 16 x 96
    const int nPart = grid.x * grid.y * grid.z;   // 12288

    if (ws_size >= (size_t)nPart * sizeof(float)) {
        // deterministic two-stage reduction
        ssim_main<<<grid, 256, 0, stream>>>(img1, img2, (float*)d_ws, gw, 0, out);
        ssim_reduce<<<1, 256, 0, stream>>>((float*)d_ws, nPart, out);
    } else {
        // fallback: atomic accumulation (still within tolerance)
        hipMemsetAsync(d_out, 0, sizeof(float), stream);
        ssim_main<<<grid, 256, 0, stream>>>(img1, img2, nullptr, gw, 1, out);
    }
}

// Round 6
// 109.203 us; speedup vs baseline: 2.0768x; 1.0546x over previous
//
#include <hip/hip_runtime.h>
#include <cmath>

#define IMG_H 512
#define IMG_W 512
#define TH 32            // tile rows (output)
#define TW 64            // tile cols (output)
#define LDSW 83          // ODD element stride (83 vf2 = 166 dwords; coprime with bank count)
#define NPLANES 96       // 32 batch * 3 channels
#define NPIX 25165824.0  // 96*512*512

typedef float vf2 __attribute__((ext_vector_type(2)));

struct GaussW { float w[11]; };

__global__ __launch_bounds__(256, 3) void ssim_main(
    const float* __restrict__ img1, const float* __restrict__ img2,
    float* __restrict__ partials, GaussW gw, int use_atomic, float* __restrict__ out)
{
    // Interleaved pair layout: (A,B) and (P,Q) share weights -> v_pk_fma_f32.
    __shared__ vf2   VAB[TH][LDSW];   // 21248 B
    __shared__ vf2   VPQ[TH][LDSW];   // 21248 B
    __shared__ float VS [TH][LDSW];   // 10624 B   (total ~53 KB -> 3 blocks/CU)
    __shared__ float wsum[4];

    const int tid = threadIdx.x;
    const int plane = blockIdx.z;
    const int tr0 = blockIdx.y * TH;
    const int tc0 = blockIdx.x * TW;
    const float* __restrict__ plane1 = img1 + ((size_t)plane << 18);  // uniform -> SGPR base
    const float* __restrict__ plane2 = img2 + ((size_t)plane << 18);

    // ---------------- Phase 1: vertical conv, packed accumulator scatter ------
    // 240 threads: one lds column j each, 11 output rows (chunk r0 = {0,11,22}).
    // Single path (no interior/edge split: round-4 showed the branch join
    // demotes the 33 live accumulators to scratch). First-touch init.
    {
        const int j = tid % 80;       // lds col
        const int chunk = tid / 80;   // 0..2 active; tid>=240 idle
        if (chunk < 3) {
            const int r0 = chunk * 11;
            const int gc = tc0 + j - 8;
            const float cmask = (gc >= 0 && gc < IMG_W) ? 1.f : 0.f;
            const int gcc = min(max(gc, 0), IMG_W - 1);   // v_med3

            vf2 aAB[11], aPQ[11];
            float aS[11];

            #pragma unroll
            for (int ii = 0; ii < 21; ++ii) {
                const int gr = tr0 + r0 - 5 + ii;
                const float rmask = (gr >= 0 && gr < IMG_H) ? cmask : 0.f;
                const int grc = min(max(gr, 0), IMG_H - 1);
                const uint32_t idx = (uint32_t)(grc * IMG_W + gcc);
                const float a = plane1[idx] * rmask;
                const float b = plane2[idx] * rmask;
                const vf2 ab = { a, b };
                const vf2 pq = ab * ab;            // v_pk_mul_f32
                const float s = a * b;
                #pragma unroll
                for (int o = 0; o < 11; ++o) {
                    if (o <= ii && ii <= o + 10) {          // compile-time predicate
                        const float wt = gw.w[ii - o];
                        const vf2 wtv = { wt, wt };
                        if (ii == o) {                       // first touch
                            aAB[o] = wtv * ab;
                            aPQ[o] = wtv * pq;
                            aS[o]  = wt * s;
                        } else {
                            aAB[o] = __builtin_elementwise_fma(wtv, ab, aAB[o]);
                            aPQ[o] = __builtin_elementwise_fma(wtv, pq, aPQ[o]);
                            aS[o]  = fmaf(wt, s, aS[o]);
                        }
                    }
                }
            }
            #pragma unroll
            for (int o = 0; o < 11; ++o) {
                const int r = r0 + o;
                if (r0 + o < TH) {   // only chunk2/o=10 is false
                    VAB[r][j] = aAB[o];        // ds_write_b64
                    VPQ[r][j] = aPQ[o];        // ds_write_b64
                    VS [r][j] = aS[o];         // ds_write_b32
                }
            }
        }
    }
    __syncthreads();

    // ---------------- Phase 2: horizontal conv, packed per-column scatter -----
    // Row index in LOW lane bits: within each half-wave r spans 0..31, so with
    // the odd stride the b64 pair-index (83r+8cg+k) mod 16 covers all 16 pairs
    // x2 (hardware minimum) and the b32 read covers all 32 banks x2 -> free.
    // (Round-5 mapping r=tid>>3 gave 8 pairs x4 = 4-way conflict, 2.3e7 cycles.)
    float lsum = 0.f;
    {
        const int r = tid & 31;        // 0..31  (low bits!)
        const int c0 = (tid >> 5) * 8; // col group 0..7
        const vf2*   __restrict__ bAB = &VAB[r][c0];
        const vf2*   __restrict__ bPQ = &VPQ[r][c0];
        const float* __restrict__ bS  = &VS [r][c0];

        vf2 mAB[8], ePQ[8];
        float e12[8];

        #pragma unroll
        for (int k = 3; k <= 20; ++k) {          // window cols c0+3 .. c0+20
            const vf2   vab = bAB[k];
            const vf2   vpq = bPQ[k];
            const float vs  = bS[k];
            #pragma unroll
            for (int c = 0; c < 8; ++c) {
                if (k - 13 <= c && c <= k - 3) {            // compile-time
                    const float wt = gw.w[k - 3 - c];
                    const vf2 wtv = { wt, wt };
                    if (k == c + 3) {                        // first touch
                        mAB[c] = wtv * vab;
                        ePQ[c] = wtv * vpq;
                        e12[c] = wt * vs;
                    } else {
                        mAB[c] = __builtin_elementwise_fma(wtv, vab, mAB[c]);
                        ePQ[c] = __builtin_elementwise_fma(wtv, vpq, ePQ[c]);
                        e12[c] = fmaf(wt, vs, e12[c]);
                    }
                }
            }
        }
        #pragma unroll
        for (int c = 0; c < 8; ++c) {
            const float a1 = mAB[c].x, a2 = mAB[c].y;
            const float den1 = fmaf(a1, a1, fmaf(a2, a2, 0.0001f)); // mu11+mu22+C1
            const float s11  = fmaf(-a1, a1, ePQ[c].x);
            const float s22  = fmaf(-a2, a2, ePQ[c].y);
            const float s12  = fmaf(-a1, a2, e12[c]);
            const float mu12 = a1 * a2;
            const float num  = fmaf(2.f, mu12, 0.0001f) * fmaf(2.f, s12, 0.0009f);
            const float den  = den1 * (s11 + s22 + 0.0009f);
            lsum = fmaf(num, __builtin_amdgcn_rcpf(den), lsum);     // rcp ~1ulp, tol 2.7e-4
        }
    }
    // block reduction
    #pragma unroll
    for (int off = 32; off; off >>= 1) lsum += __shfl_down(lsum, off, 64);
    if ((tid & 63) == 0) wsum[tid >> 6] = lsum;
    __syncthreads();
    if (tid == 0) {
        const float bs = wsum[0] + wsum[1] + wsum[2] + wsum[3];
        if (use_atomic) {
            atomicAdd(out, bs * (float)(1.0 / NPIX));
        } else {
            const int bId = (blockIdx.z * gridDim.y + blockIdx.y) * gridDim.x + blockIdx.x;
            partials[bId] = bs;
        }
    }
}

__global__ __launch_bounds__(256) void ssim_reduce(
    const float* __restrict__ partials, int n, float* __restrict__ out)
{
    const int tid = threadIdx.x;
    double s = 0.0;
    for (int i = tid; i < n; i += 256) s += (double)partials[i];
    #pragma unroll
    for (int off = 32; off; off >>= 1) s += __shfl_down(s, off, 64);
    __shared__ double ws[4];
    if ((tid & 63) == 0) ws[tid >> 6] = s;
    __syncthreads();
    if (tid == 0) out[0] = (float)(((ws[0] + ws[1]) + (ws[2] + ws[3])) / NPIX);
}

extern "C" void kernel_launch(void* const* d_in, const int* in_sizes, int n_in,
                              void* d_out, int out_size, void* d_ws, size_t ws_size,
                              hipStream_t stream) {
    const float* img1 = (const float*)d_in[0];
    const float* img2 = (const float*)d_in[1];
    float* out = (float*)d_out;

    // Gaussian window (host, double precision, normalized)
    GaussW gw;
    {
        double g[11], sum = 0.0;
        for (int i = 0; i < 11; ++i) {
            const double c = (double)(i - 5);
            g[i] = std::exp(-(c * c) / 4.5);   // 2*sigma^2 = 4.5
            sum += g[i];
        }
        for (int i = 0; i < 11; ++i) gw.w[i] = (float)(g[i] / sum);
    }

    dim3 grid(IMG_W / TW, IMG_H / TH, NPLANES);   // 8 x 16 x 96
    const int nPart = grid.x * grid.y * grid.z;   // 12288

    if (ws_size >= (size_t)nPart * sizeof(float)) {
        // deterministic two-stage reduction
        ssim_main<<<grid, 256, 0, stream>>>(img1, img2, (float*)d_ws, gw, 0, out);
        ssim_reduce<<<1, 256, 0, stream>>>((float*)d_ws, nPart, out);
    } else {
        // fallback: atomic accumulation (still within tolerance)
        hipMemsetAsync(d_out, 0, sizeof(float), stream);
        ssim_main<<<grid, 256, 0, stream>>>(img1, img2, nullptr, gw, 1, out);
    }
}